// Round 2
// baseline (409.460 us; speedup 1.0000x reference)
//
#include <hip/hip_runtime.h>

// Problem constants (fixed by setup_inputs)
#define NB 16
#define NE 8
#define NH 512
#define NW 1024
#define HW (NH * NW)            // 524288 pixels per image
#define CHUNKS 128              // blocks per image (2048 total, 8 blocks/CU)
#define TPB 256
#define PIX_PER_CHUNK (HW / CHUNKS)         // 4096
#define GRP (PIX_PER_CHUNK / (TPB * 4))     // 4 groups of 4 pixels per thread
#define ACC_STRIDE 40           // per-b: cnt[4], sumsq[4], sums[4][8]

// Native clang vector type: __builtin_nontemporal_load requires a pointer to
// scalar/vector-of-scalar, not HIP_vector_type<float,4>.
typedef float floatx4 __attribute__((ext_vector_type(4)));

// Non-temporal float4 load: pred is a read-once 256 MiB stream, don't let it
// thrash L2 (the poison fills destroy any cross-iteration L3 residency anyway).
static __device__ __forceinline__ floatx4 nt_load4(const float* p) {
    return __builtin_nontemporal_load(reinterpret_cast<const floatx4*>(p));
}

// Stage 1: per-block partial statistics, atomically accumulated into acc[b][40].
// Label 0 contributes nothing (binary_label == (label>0) zeroes pred_roi), so we
// only track labels 1..4. binary_label input is therefore never read.
//
// CHANNEL-MAJOR restructure: the previous version issued 9 loads at 2 MiB
// stride per thread-group (8 pred channels + labels), i.e. ~18K interleaved
// fine-grained streams device-wide -> DRAM row thrash, read BW stuck at
// ~4.5 TB/s. Now: labels for the block's 4096-px chunk are read ONCE and
// packed into 4 u32 registers; then channels are swept sequentially, each
// pass reading one contiguous 16 KiB run per block (1 stream/block). A
// 2-channel-deep rotating prefetch (buf[3][GRP], statically indexed under full
// unroll) keeps 8 loads in flight per wave without ever draining vmcnt to 0.
// All per-thread partials are accumulated in the bit-identical order of the
// previous kernel (g-major, p, l; ssq per (g,p) summed over e first).
__global__ __launch_bounds__(TPB) void cluster_partial(
    const float* __restrict__ pred, const int* __restrict__ lab,
    float* __restrict__ acc)
{
    const int b     = blockIdx.x / CHUNKS;
    const int chunk = blockIdx.x % CHUNKS;
    const int t     = threadIdx.x;

    const float* predb = pred + (long)b * NE * HW + chunk * PIX_PER_CHUNK;
    const int*   labb  = lab  + (long)b * HW      + chunk * PIX_PER_CHUNK;
    const int    toff  = t << 2;

    // ---- label phase: 4 int4 loads, pack 4 labels/u32 (labels are 0..4) ----
    int4 L[GRP];
#pragma unroll
    for (int g = 0; g < GRP; ++g)
        L[g] = *reinterpret_cast<const int4*>(labb + g * (TPB * 4) + toff);

    // issue pred prefetch for channels 0 and 1 — overlaps label processing
    floatx4 buf[3][GRP];
#pragma unroll
    for (int g = 0; g < GRP; ++g)
        buf[0][g] = nt_load4(predb + 0l * HW + g * (TPB * 4) + toff);
#pragma unroll
    for (int g = 0; g < GRP; ++g)
        buf[1][g] = nt_load4(predb + 1l * HW + g * (TPB * 4) + toff);

    unsigned lp[GRP];
    float cnt[4] = {0.f, 0.f, 0.f, 0.f};
#pragma unroll
    for (int g = 0; g < GRP; ++g) {
        lp[g] = (unsigned)L[g].x | ((unsigned)L[g].y << 8) |
                ((unsigned)L[g].z << 16) | ((unsigned)L[g].w << 24);
        const int lbs[4] = {L[g].x, L[g].y, L[g].z, L[g].w};
#pragma unroll
        for (int p = 0; p < 4; ++p)
#pragma unroll
            for (int l = 0; l < 4; ++l)
                cnt[l] += (lbs[p] == l + 1) ? 1.0f : 0.0f;
    }

    float sums[4][NE];
#pragma unroll
    for (int l = 0; l < 4; ++l)
#pragma unroll
        for (int e = 0; e < NE; ++e) sums[l][e] = 0.f;
    float ssqp[GRP * 4];            // per-(g,p) sum over e of v^2 (unmasked)
#pragma unroll
    for (int i = 0; i < GRP * 4; ++i) ssqp[i] = 0.f;

    // ---- channel sweep: one contiguous 16 KiB run per block per pass ----
#pragma unroll
    for (int e = 0; e < NE; ++e) {
        if (e + 2 < NE) {
#pragma unroll
            for (int g = 0; g < GRP; ++g)
                buf[(e + 2) % 3][g] =
                    nt_load4(predb + (long)(e + 2) * HW + g * (TPB * 4) + toff);
        }
#pragma unroll
        for (int g = 0; g < GRP; ++g) {
            const floatx4  v  = buf[e % 3][g];
            const unsigned lw = lp[g];
            const float vv[4] = {v.x, v.y, v.z, v.w};
#pragma unroll
            for (int p = 0; p < 4; ++p) {
                const int   lb = (int)((lw >> (8 * p)) & 0xffu);
                const float x  = vv[p];
                ssqp[g * 4 + p] = fmaf(x, x, ssqp[g * 4 + p]);
#pragma unroll
                for (int l = 0; l < 4; ++l)
                    sums[l][e] += (lb == l + 1) ? x : 0.0f;  // == fmaf(m,x,s)
            }
        }
    }

    // ---- apply label masks to the per-(g,p) sumsq partials (old order) ----
    float ssq_acc[4] = {0.f, 0.f, 0.f, 0.f};
#pragma unroll
    for (int g = 0; g < GRP; ++g) {
        const unsigned lw = lp[g];
#pragma unroll
        for (int p = 0; p < 4; ++p) {
            const int lb = (int)((lw >> (8 * p)) & 0xffu);
#pragma unroll
            for (int l = 0; l < 4; ++l)
                ssq_acc[l] += (lb == l + 1) ? ssqp[g * 4 + p] : 0.0f;
        }
    }

    // Pack 40 per-thread partials; wave(64)-level shuffle reduction.
    float vals[ACC_STRIDE];
#pragma unroll
    for (int l = 0; l < 4; ++l) {
        vals[l]     = cnt[l];
        vals[4 + l] = ssq_acc[l];
#pragma unroll
        for (int e = 0; e < NE; ++e) vals[8 + l * NE + e] = sums[l][e];
    }
#pragma unroll
    for (int i = 0; i < ACC_STRIDE; ++i) {
        float vv = vals[i];
        vv += __shfl_down(vv, 32);
        vv += __shfl_down(vv, 16);
        vv += __shfl_down(vv, 8);
        vv += __shfl_down(vv, 4);
        vv += __shfl_down(vv, 2);
        vv += __shfl_down(vv, 1);
        vals[i] = vv;
    }

    __shared__ float red[TPB / 64][ACC_STRIDE];
    const int wave = t >> 6;
    const int lane = t & 63;
    if (lane == 0) {
#pragma unroll
        for (int i = 0; i < ACC_STRIDE; ++i) red[wave][i] = vals[i];
    }
    __syncthreads();
    if (t < ACC_STRIDE) {
        float s = red[0][t] + red[1][t] + red[2][t] + red[3][t];
        atomicAdd(&acc[b * ACC_STRIDE + t], s);
    }
}

// Stage 2: tiny finalize — one thread per batch image, wave-reduce, write scalar.
__global__ __launch_bounds__(64) void cluster_finalize(
    const float* __restrict__ acc, float* __restrict__ out)
{
    const int t = threadIdx.x;
    float Lb = 0.f;
    if (t < NB) {
        const float* a = acc + t * ACC_STRIDE;
        float mu[4][NE];   // cluster means for labels 0..3 (mu_d); mu[0] == 0
#pragma unroll
        for (int e = 0; e < NE; ++e) mu[0][e] = 0.f;

        float Lvar = 0.f;
#pragma unroll
        for (int l = 1; l <= 4; ++l) {
            const float c   = a[l - 1];
            const float ssq = a[4 + (l - 1)];
            float mloc[NE];
            float musq = 0.f;
#pragma unroll
            for (int e = 0; e < NE; ++e) {
                mloc[e] = a[8 + (l - 1) * NE + e] / c;
                musq = fmaf(mloc[e], mloc[e], musq);
            }
            const float frob = ssq - c * musq;
            const float n = (frob > 0.f) ? sqrtf(frob) : 0.f;
            const float dv = n - 0.5f;               // DELTA_V = 0.5
            Lvar += (n > 0.5f) ? dv * dv : 0.f;
            if (l < 4) {
#pragma unroll
                for (int e = 0; e < NE; ++e) mu[l][e] = mloc[e];
            }
        }
        Lvar *= 0.25f;  // / C

        float Ldist = 0.f;
#pragma unroll
        for (int i = 0; i < 4; ++i)
#pragma unroll
            for (int j = i + 1; j < 4; ++j) {
                float dsq = 0.f;
#pragma unroll
                for (int e = 0; e < NE; ++e) {
                    const float d = mu[i][e] - mu[j][e];
                    dsq = fmaf(d, d, dsq);
                }
                float h;
                if (dsq > 0.f) {
                    const float d = sqrtf(dsq);
                    float r = 3.0f - d;              // DELTA_D = 3.0
                    r = (r > 0.f) ? r : 0.f;
                    h = r * r;
                } else {
                    h = 9.0f;                        // DELTA_D^2
                }
                Ldist += 2.0f * h;                   // both (i,j) and (j,i)
            }

        Lb = (Lvar + Ldist) * (1.0f / NB);           // mean over B of both terms
    }
    Lb += __shfl_down(Lb, 32);
    Lb += __shfl_down(Lb, 16);
    Lb += __shfl_down(Lb, 8);
    Lb += __shfl_down(Lb, 4);
    Lb += __shfl_down(Lb, 2);
    Lb += __shfl_down(Lb, 1);
    if (t == 0) out[0] = Lb;
}

extern "C" void kernel_launch(void* const* d_in, const int* in_sizes, int n_in,
                              void* d_out, int out_size, void* d_ws, size_t ws_size,
                              hipStream_t stream) {
    const float* pred = (const float*)d_in[0];
    // d_in[1] = binary_label: unused — it is exactly (instance_label > 0).
    const int* lab = (const int*)d_in[2];
    float* out = (float*)d_out;
    float* acc = (float*)d_ws;   // NB*40 floats = 2560 B, ws is poisoned -> zero it

    (void)hipMemsetAsync(acc, 0, NB * ACC_STRIDE * sizeof(float), stream);
    cluster_partial<<<NB * CHUNKS, TPB, 0, stream>>>(pred, lab, acc);
    cluster_finalize<<<1, 64, 0, stream>>>(acc, out);
}

// Round 3
// 404.685 us; speedup vs baseline: 1.0118x; 1.0118x over previous
//
#include <hip/hip_runtime.h>

// Problem constants (fixed by setup_inputs)
#define NB 16
#define NE 8
#define NH 512
#define NW 1024
#define HW (NH * NW)            // 524288 pixels per image
#define CHUNKS 128              // blocks per image (2048 total, 8 blocks/CU)
#define TPB 256
#define PIX_PER_CHUNK (HW / CHUNKS)         // 4096
#define GRP (PIX_PER_CHUNK / (TPB * 4))     // 4 groups of 4 pixels per thread
#define ACC_STRIDE 40           // per-b: cnt[4], sumsq[4], sums[4][8]

// Native clang vector type (also works for plain dereference loads).
typedef float floatx4 __attribute__((ext_vector_type(4)));

// PLAIN cached float4 load. Round-2's __builtin_nontemporal_load (nt flag,
// bypasses L2 allocation) coincided with a 66->81us regression of this kernel;
// L2 is the read-combining stage between 1KiB wave requests and HBM bursts,
// so nt on a streaming read path is the prime regression suspect. This round
// isolates that variable: identical structure, nt removed.
static __device__ __forceinline__ floatx4 ld4(const float* p) {
    return *reinterpret_cast<const floatx4*>(p);
}

// Stage 1: per-block partial statistics, atomically accumulated into acc[b][40].
// Label 0 contributes nothing (binary_label == (label>0) zeroes pred_roi), so we
// only track labels 1..4. binary_label input is therefore never read.
//
// CHANNEL-MAJOR structure: labels for the block's 4096-px chunk are read ONCE
// and packed into 4 u32 registers; then channels are swept sequentially, each
// pass reading one contiguous 16 KiB run per block (1 stream/block vs 9
// interleaved 2MiB-strided streams). A 2-channel-deep rotating prefetch
// (buf[3][GRP], statically indexed under full unroll) keeps 8 loads in flight
// per wave without ever draining vmcnt to 0. All per-thread partials are
// accumulated in the bit-identical order of the round-0 kernel.
__global__ __launch_bounds__(TPB) void cluster_partial(
    const float* __restrict__ pred, const int* __restrict__ lab,
    float* __restrict__ acc)
{
    const int b     = blockIdx.x / CHUNKS;
    const int chunk = blockIdx.x % CHUNKS;
    const int t     = threadIdx.x;

    const float* predb = pred + (long)b * NE * HW + chunk * PIX_PER_CHUNK;
    const int*   labb  = lab  + (long)b * HW      + chunk * PIX_PER_CHUNK;
    const int    toff  = t << 2;

    // ---- label phase: 4 int4 loads, pack 4 labels/u32 (labels are 0..4) ----
    int4 L[GRP];
#pragma unroll
    for (int g = 0; g < GRP; ++g)
        L[g] = *reinterpret_cast<const int4*>(labb + g * (TPB * 4) + toff);

    // issue pred prefetch for channels 0 and 1 — overlaps label processing
    floatx4 buf[3][GRP];
#pragma unroll
    for (int g = 0; g < GRP; ++g)
        buf[0][g] = ld4(predb + 0l * HW + g * (TPB * 4) + toff);
#pragma unroll
    for (int g = 0; g < GRP; ++g)
        buf[1][g] = ld4(predb + 1l * HW + g * (TPB * 4) + toff);

    unsigned lp[GRP];
    float cnt[4] = {0.f, 0.f, 0.f, 0.f};
#pragma unroll
    for (int g = 0; g < GRP; ++g) {
        lp[g] = (unsigned)L[g].x | ((unsigned)L[g].y << 8) |
                ((unsigned)L[g].z << 16) | ((unsigned)L[g].w << 24);
        const int lbs[4] = {L[g].x, L[g].y, L[g].z, L[g].w};
#pragma unroll
        for (int p = 0; p < 4; ++p)
#pragma unroll
            for (int l = 0; l < 4; ++l)
                cnt[l] += (lbs[p] == l + 1) ? 1.0f : 0.0f;
    }

    float sums[4][NE];
#pragma unroll
    for (int l = 0; l < 4; ++l)
#pragma unroll
        for (int e = 0; e < NE; ++e) sums[l][e] = 0.f;
    float ssqp[GRP * 4];            // per-(g,p) sum over e of v^2 (unmasked)
#pragma unroll
    for (int i = 0; i < GRP * 4; ++i) ssqp[i] = 0.f;

    // ---- channel sweep: one contiguous 16 KiB run per block per pass ----
#pragma unroll
    for (int e = 0; e < NE; ++e) {
        if (e + 2 < NE) {
#pragma unroll
            for (int g = 0; g < GRP; ++g)
                buf[(e + 2) % 3][g] =
                    ld4(predb + (long)(e + 2) * HW + g * (TPB * 4) + toff);
        }
#pragma unroll
        for (int g = 0; g < GRP; ++g) {
            const floatx4  v  = buf[e % 3][g];
            const unsigned lw = lp[g];
            const float vv[4] = {v.x, v.y, v.z, v.w};
#pragma unroll
            for (int p = 0; p < 4; ++p) {
                const int   lb = (int)((lw >> (8 * p)) & 0xffu);
                const float x  = vv[p];
                ssqp[g * 4 + p] = fmaf(x, x, ssqp[g * 4 + p]);
#pragma unroll
                for (int l = 0; l < 4; ++l)
                    sums[l][e] += (lb == l + 1) ? x : 0.0f;  // == fmaf(m,x,s)
            }
        }
    }

    // ---- apply label masks to the per-(g,p) sumsq partials (old order) ----
    float ssq_acc[4] = {0.f, 0.f, 0.f, 0.f};
#pragma unroll
    for (int g = 0; g < GRP; ++g) {
        const unsigned lw = lp[g];
#pragma unroll
        for (int p = 0; p < 4; ++p) {
            const int lb = (int)((lw >> (8 * p)) & 0xffu);
#pragma unroll
            for (int l = 0; l < 4; ++l)
                ssq_acc[l] += (lb == l + 1) ? ssqp[g * 4 + p] : 0.0f;
        }
    }

    // Pack 40 per-thread partials; wave(64)-level shuffle reduction.
    float vals[ACC_STRIDE];
#pragma unroll
    for (int l = 0; l < 4; ++l) {
        vals[l]     = cnt[l];
        vals[4 + l] = ssq_acc[l];
#pragma unroll
        for (int e = 0; e < NE; ++e) vals[8 + l * NE + e] = sums[l][e];
    }
#pragma unroll
    for (int i = 0; i < ACC_STRIDE; ++i) {
        float vv = vals[i];
        vv += __shfl_down(vv, 32);
        vv += __shfl_down(vv, 16);
        vv += __shfl_down(vv, 8);
        vv += __shfl_down(vv, 4);
        vv += __shfl_down(vv, 2);
        vv += __shfl_down(vv, 1);
        vals[i] = vv;
    }

    __shared__ float red[TPB / 64][ACC_STRIDE];
    const int wave = t >> 6;
    const int lane = t & 63;
    if (lane == 0) {
#pragma unroll
        for (int i = 0; i < ACC_STRIDE; ++i) red[wave][i] = vals[i];
    }
    __syncthreads();
    if (t < ACC_STRIDE) {
        float s = red[0][t] + red[1][t] + red[2][t] + red[3][t];
        atomicAdd(&acc[b * ACC_STRIDE + t], s);
    }
}

// Stage 2: tiny finalize — one thread per batch image, wave-reduce, write scalar.
__global__ __launch_bounds__(64) void cluster_finalize(
    const float* __restrict__ acc, float* __restrict__ out)
{
    const int t = threadIdx.x;
    float Lb = 0.f;
    if (t < NB) {
        const float* a = acc + t * ACC_STRIDE;
        float mu[4][NE];   // cluster means for labels 0..3 (mu_d); mu[0] == 0
#pragma unroll
        for (int e = 0; e < NE; ++e) mu[0][e] = 0.f;

        float Lvar = 0.f;
#pragma unroll
        for (int l = 1; l <= 4; ++l) {
            const float c   = a[l - 1];
            const float ssq = a[4 + (l - 1)];
            float mloc[NE];
            float musq = 0.f;
#pragma unroll
            for (int e = 0; e < NE; ++e) {
                mloc[e] = a[8 + (l - 1) * NE + e] / c;
                musq = fmaf(mloc[e], mloc[e], musq);
            }
            const float frob = ssq - c * musq;
            const float n = (frob > 0.f) ? sqrtf(frob) : 0.f;
            const float dv = n - 0.5f;               // DELTA_V = 0.5
            Lvar += (n > 0.5f) ? dv * dv : 0.f;
            if (l < 4) {
#pragma unroll
                for (int e = 0; e < NE; ++e) mu[l][e] = mloc[e];
            }
        }
        Lvar *= 0.25f;  // / C

        float Ldist = 0.f;
#pragma unroll
        for (int i = 0; i < 4; ++i)
#pragma unroll
            for (int j = i + 1; j < 4; ++j) {
                float dsq = 0.f;
#pragma unroll
                for (int e = 0; e < NE; ++e) {
                    const float d = mu[i][e] - mu[j][e];
                    dsq = fmaf(d, d, dsq);
                }
                float h;
                if (dsq > 0.f) {
                    const float d = sqrtf(dsq);
                    float r = 3.0f - d;              // DELTA_D = 3.0
                    r = (r > 0.f) ? r : 0.f;
                    h = r * r;
                } else {
                    h = 9.0f;                        // DELTA_D^2
                }
                Ldist += 2.0f * h;                   // both (i,j) and (j,i)
            }

        Lb = (Lvar + Ldist) * (1.0f / NB);           // mean over B of both terms
    }
    Lb += __shfl_down(Lb, 32);
    Lb += __shfl_down(Lb, 16);
    Lb += __shfl_down(Lb, 8);
    Lb += __shfl_down(Lb, 4);
    Lb += __shfl_down(Lb, 2);
    Lb += __shfl_down(Lb, 1);
    if (t == 0) out[0] = Lb;
}

extern "C" void kernel_launch(void* const* d_in, const int* in_sizes, int n_in,
                              void* d_out, int out_size, void* d_ws, size_t ws_size,
                              hipStream_t stream) {
    const float* pred = (const float*)d_in[0];
    // d_in[1] = binary_label: unused — it is exactly (instance_label > 0).
    const int* lab = (const int*)d_in[2];
    float* out = (float*)d_out;
    float* acc = (float*)d_ws;   // NB*40 floats = 2560 B, ws is poisoned -> zero it

    (void)hipMemsetAsync(acc, 0, NB * ACC_STRIDE * sizeof(float), stream);
    cluster_partial<<<NB * CHUNKS, TPB, 0, stream>>>(pred, lab, acc);
    cluster_finalize<<<1, 64, 0, stream>>>(acc, out);
}